// Round 1
// baseline (1999.927 us; speedup 1.0000x reference)
//
#include <hip/hip_runtime.h>
#include <math.h>

// ---------------------------------------------------------------- constants
constexpr int N  = 40000;   // nodes
constexpr int D  = 128;     // latent dim
constexpr int E  = 640000;  // spatial edges
constexpr int Bg = 8;       // graphs
constexpr int Sg = 5000;    // nodes per graph
constexpr int KN = 6;       // knn
constexpr int FF = 256;     // ffn hidden
constexpr int QT = 79;      // ceil(Sg/64) query/cand tiles per graph
constexpr int LGCAP = 320;  // max in-degree supported in spatial GAT (actual ~45)

// ---------------------------------------------------------------- GEMM: out = A@W + bias (+res) (+relu6)
// A: [N x Kdim] (lda), W: [Kdim x ?] (ldw, col offset cb=blockIdx.y*128)
// out: [N x ldo]. res (optional): [N x 128], only valid when gridDim.y==1.
__global__ __launch_bounds__(256) void gemm_k(
    const float* __restrict__ A, int lda,
    const float* __restrict__ Wm, int ldw,
    const float* __restrict__ bias,
    const float* __restrict__ res,
    float* __restrict__ out, int ldo,
    int Kdim, int act)
{
    __shared__ float as[64][36];    // 64 rows x 32 k (pad 36 -> bank spread, 16B aligned)
    __shared__ float ws[32][128];   // 32 k x 128 cols
    int tid = threadIdx.x;
    int tr = tid >> 4, tc = tid & 15;
    int r0 = blockIdx.x * 64;
    int cb = blockIdx.y * 128;

    float acc[4][8];
#pragma unroll
    for (int j = 0; j < 4; ++j)
#pragma unroll
        for (int m = 0; m < 8; ++m) acc[j][m] = 0.f;

    for (int kt = 0; kt < Kdim; kt += 32) {
#pragma unroll
        for (int i = 0; i < 2; ++i) {           // stage A tile 64x32
            int c2 = i * 256 + tid;
            int row = c2 >> 3, k4 = (c2 & 7) * 4;
            *(float4*)&as[row][k4] = *(const float4*)&A[(size_t)(r0 + row) * lda + kt + k4];
        }
#pragma unroll
        for (int i = 0; i < 4; ++i) {           // stage W tile 32x128
            int c2 = i * 256 + tid;
            int row = c2 >> 5, c4 = (c2 & 31) * 4;
            *(float4*)&ws[row][c4] = *(const float4*)&Wm[(size_t)(kt + row) * ldw + cb + c4];
        }
        __syncthreads();
#pragma unroll 8
        for (int k = 0; k < 32; ++k) {
            float a[4], b[8];
#pragma unroll
            for (int j = 0; j < 4; ++j) a[j] = as[tr + 16 * j][k];
#pragma unroll
            for (int m = 0; m < 8; ++m) b[m] = ws[k][tc + 16 * m];
#pragma unroll
            for (int j = 0; j < 4; ++j)
#pragma unroll
                for (int m = 0; m < 8; ++m) acc[j][m] = fmaf(a[j], b[m], acc[j][m]);
        }
        __syncthreads();
    }
#pragma unroll
    for (int j = 0; j < 4; ++j) {
        int r = r0 + tr + 16 * j;
#pragma unroll
        for (int m = 0; m < 8; ++m) {
            int c = tc + 16 * m;
            float v = acc[j][m] + bias[cb + c];
            if (res) v += res[(size_t)r * 128 + c];
            if (act) v = fminf(fmaxf(v, 0.f), 6.f);
            out[(size_t)r * ldo + cb + c] = v;
        }
    }
}

// ---------------------------------------------------------------- per-row squared norm (wave per row)
__global__ __launch_bounds__(256) void sqnorm_k(const float* __restrict__ x, float* __restrict__ sqn)
{
    int w = threadIdx.x >> 6, lane = threadIdx.x & 63;
    int row = blockIdx.x * 4 + w;
    float v0 = x[(size_t)row * 128 + lane];
    float v1 = x[(size_t)row * 128 + 64 + lane];
    float s = v0 * v0 + v1 * v1;
#pragma unroll
    for (int off = 32; off; off >>= 1) s += __shfl_xor(s, off);
    if (lane == 0) sqn[row] = s;
}

// ---------------------------------------------------------------- kNN: per graph all-pairs d2, top-6 per query row
// block: 256 threads = (tr,tc) 16x16; 64 queries/block; cand tiles of 64.
// thread owns queries {tr+16j} (j<4) and per tile cands {tc+16m} (m<4).
__global__ __launch_bounds__(256) void knn_k(const float* __restrict__ x,
                                             const float* __restrict__ sqn,
                                             int* __restrict__ knn_idx)
{
    __shared__ float Qs[64][132];   // 132: 16B-aligned rows + bank spread
    __shared__ float Cs[64][132];   // aliased as merge buffer after main loop
    __shared__ float csq[64];
    int g = blockIdx.x / QT, qt = blockIdx.x % QT;
    int gbase = g * Sg;
    int q0 = qt * 64;
    int tid = threadIdx.x;
    int tr = tid >> 4, tc = tid & 15;

    // stage queries (pad rows >= Sg with zeros)
#pragma unroll
    for (int i = 0; i < 8; ++i) {
        int c2 = i * 256 + tid;
        int row = c2 >> 5, k4 = (c2 & 31) * 4;
        int qr = q0 + row;
        float4 v = make_float4(0.f, 0.f, 0.f, 0.f);
        if (qr < Sg) v = *(const float4*)&x[(size_t)(gbase + qr) * 128 + k4];
        *(float4*)&Qs[row][k4] = v;
    }

    float dist6[4][6]; int idx6[4][6]; float mx[4]; int slot[4];
#pragma unroll
    for (int j = 0; j < 4; ++j) {
        mx[j] = __builtin_inff(); slot[j] = 0;
#pragma unroll
        for (int t = 0; t < 6; ++t) { dist6[j][t] = __builtin_inff(); idx6[j][t] = 0; }
    }

    for (int ct = 0; ct < QT; ++ct) {
        int c0 = ct * 64;
        __syncthreads();
#pragma unroll
        for (int i = 0; i < 8; ++i) {       // stage candidate tile
            int c2 = i * 256 + tid;
            int row = c2 >> 5, k4 = (c2 & 31) * 4;
            int cr = c0 + row;
            float4 v = make_float4(0.f, 0.f, 0.f, 0.f);
            if (cr < Sg) v = *(const float4*)&x[(size_t)(gbase + cr) * 128 + k4];
            *(float4*)&Cs[row][k4] = v;
        }
        if (tid < 64) csq[tid] = (c0 + tid < Sg) ? sqn[gbase + c0 + tid] : __builtin_inff();
        __syncthreads();

        float acc[4][4];
#pragma unroll
        for (int j = 0; j < 4; ++j)
#pragma unroll
            for (int m = 0; m < 4; ++m) acc[j][m] = 0.f;

#pragma unroll 2
        for (int k4 = 0; k4 < 128; k4 += 4) {
            float4 a[4], b[4];
#pragma unroll
            for (int j = 0; j < 4; ++j) a[j] = *(const float4*)&Qs[tr + 16 * j][k4];
#pragma unroll
            for (int m = 0; m < 4; ++m) b[m] = *(const float4*)&Cs[tc + 16 * m][k4];
#pragma unroll
            for (int j = 0; j < 4; ++j)
#pragma unroll
                for (int m = 0; m < 4; ++m) {
                    acc[j][m] = fmaf(a[j].x, b[m].x, acc[j][m]);
                    acc[j][m] = fmaf(a[j].y, b[m].y, acc[j][m]);
                    acc[j][m] = fmaf(a[j].z, b[m].z, acc[j][m]);
                    acc[j][m] = fmaf(a[j].w, b[m].w, acc[j][m]);
                }
        }

        // ranking key: |xc|^2 - 2*q.c  (query norm constant per row -> same order)
#pragma unroll
        for (int m = 0; m < 4; ++m) {
            int cl = c0 + tc + 16 * m;
            float cs = csq[tc + 16 * m];
#pragma unroll
            for (int j = 0; j < 4; ++j) {
                int ql = q0 + tr + 16 * j;
                float dv = fmaf(-2.f, acc[j][m], cs);
                if (cl != ql && dv < mx[j]) {
#pragma unroll
                    for (int t = 0; t < 6; ++t)
                        if (t == slot[j]) { dist6[j][t] = dv; idx6[j][t] = cl; }
                    float m2 = dist6[j][0]; int s2 = 0;
#pragma unroll
                    for (int t = 1; t < 6; ++t)
                        if (dist6[j][t] > m2) { m2 = dist6[j][t]; s2 = t; }
                    mx[j] = m2; slot[j] = s2;
                }
            }
        }
    }

    // tree-merge the 16 tc-partials per (tr,j) query row; Cs reused as buffer
    float* mbuf = &Cs[0][0];
    for (int s = 8; s >= 1; s >>= 1) {
        __syncthreads();
        if (tc >= s && tc < 2 * s) {
            int base = (tr * 8 + (tc - s)) * 48;
#pragma unroll
            for (int j = 0; j < 4; ++j)
#pragma unroll
                for (int t = 0; t < 6; ++t) {
                    mbuf[base + (j * 6 + t) * 2]     = dist6[j][t];
                    mbuf[base + (j * 6 + t) * 2 + 1] = __int_as_float(idx6[j][t]);
                }
        }
        __syncthreads();
        if (tc < s) {
            int base = (tr * 8 + tc) * 48;
#pragma unroll
            for (int j = 0; j < 4; ++j)
#pragma unroll
                for (int t = 0; t < 6; ++t) {
                    float dv = mbuf[base + (j * 6 + t) * 2];
                    int ci = __float_as_int(mbuf[base + (j * 6 + t) * 2 + 1]);
                    if (dv < mx[j]) {
#pragma unroll
                        for (int u = 0; u < 6; ++u)
                            if (u == slot[j]) { dist6[j][u] = dv; idx6[j][u] = ci; }
                        float m2 = dist6[j][0]; int s2 = 0;
#pragma unroll
                        for (int u = 1; u < 6; ++u)
                            if (dist6[j][u] > m2) { m2 = dist6[j][u]; s2 = u; }
                        mx[j] = m2; slot[j] = s2;
                    }
                }
        }
    }
    if (tc == 0) {
#pragma unroll
        for (int j = 0; j < 4; ++j) {
            int ql = q0 + tr + 16 * j;
            if (ql < Sg) {
#pragma unroll
                for (int t = 0; t < 6; ++t)
                    knn_idx[(size_t)(gbase + ql) * 6 + t] = gbase + idx6[j][t];
            }
        }
    }
}

// ---------------------------------------------------------------- CSR build
__global__ __launch_bounds__(256) void hist_k(const int* __restrict__ dstA, int* __restrict__ deg)
{
    int e = blockIdx.x * 256 + threadIdx.x;
    atomicAdd(&deg[dstA[e]], 1);
}

__global__ __launch_bounds__(1024) void scan_k(const int* __restrict__ deg, int* __restrict__ rowptr)
{
    __shared__ int ps[1024];
    int t = threadIdx.x;
    const int chunk = 40;   // 1024*40 >= N
    int base = t * chunk;
    int s = 0;
    for (int k = 0; k < chunk; ++k) { int i = base + k; if (i < N) s += deg[i]; }
    ps[t] = s;
    __syncthreads();
    for (int off = 1; off < 1024; off <<= 1) {
        int v = (t >= off) ? ps[t - off] : 0;
        __syncthreads();
        ps[t] += v;
        __syncthreads();
    }
    int run = ps[t] - s;    // exclusive base
    for (int k = 0; k < chunk; ++k) {
        int i = base + k;
        if (i < N) { rowptr[i] = run; run += deg[i]; }
    }
    if (t == 0) rowptr[N] = E;
}

__global__ __launch_bounds__(256) void scatter_k(const int* __restrict__ srcA, const int* __restrict__ dstA,
                                                 const float* __restrict__ ea,
                                                 const int* __restrict__ rowptr, int* __restrict__ cnt,
                                                 int* __restrict__ csr_src, float* __restrict__ csr_ea)
{
    int e = blockIdx.x * 256 + threadIdx.x;
    int d = dstA[e];
    int pos = rowptr[d] + atomicAdd(&cnt[d], 1);
    csr_src[pos] = srcA[e];
    csr_ea[pos] = ea[e];
}

// ---------------------------------------------------------------- spatial GATv2 (wave per dst node)
__global__ __launch_bounds__(256) void spatial_gat_k(
    const float* __restrict__ xl, const float* __restrict__ xr,
    const int* __restrict__ rowptr, const int* __restrict__ csr_src, const float* __restrict__ csr_ea,
    const float* __restrict__ att, const float* __restrict__ wse, const float* __restrict__ bias,
    float* __restrict__ ch2)
{
    __shared__ float lg[4][LGCAP];
    int w = threadIdx.x >> 6, lane = threadIdx.x & 63;
    int dst = blockIdx.x * 4 + w;
    int base = rowptr[dst];
    int deg = rowptr[dst + 1] - base;
    if (deg > LGCAP) deg = LGCAP;
    float xr0 = xr[(size_t)dst * 128 + lane], xr1 = xr[(size_t)dst * 128 + 64 + lane];
    float at0 = att[lane], at1 = att[64 + lane];
    float we0 = wse[lane], we1 = wse[64 + lane];
    float m = -1e30f;
    for (int i = 0; i < deg; ++i) {
        int s = csr_src[base + i];
        float ea = csr_ea[base + i];
        float h0 = xl[(size_t)s * 128 + lane] + xr0 + ea * we0;
        float h1 = xl[(size_t)s * 128 + 64 + lane] + xr1 + ea * we1;
        h0 = h0 > 0.f ? h0 : 0.2f * h0;
        h1 = h1 > 0.f ? h1 : 0.2f * h1;
        float p = h0 * at0 + h1 * at1;
#pragma unroll
        for (int off = 32; off; off >>= 1) p += __shfl_xor(p, off);
        if (lane == 0) lg[w][i] = p;
        m = fmaxf(m, p);
    }
    __syncthreads();
    float sum = 0.f;
    for (int i = lane; i < deg; i += 64) {
        float ev = __expf(lg[w][i] - m);
        lg[w][i] = ev;
        sum += ev;
    }
#pragma unroll
    for (int off = 32; off; off >>= 1) sum += __shfl_xor(sum, off);
    float inv = 1.f / sum;  // deg==0 -> inf but unused (loops skipped)
    __syncthreads();
    float o0 = 0.f, o1 = 0.f;
    for (int i = 0; i < deg; ++i) {
        float a = lg[w][i] * inv;
        int s = csr_src[base + i];
        o0 = fmaf(a, xl[(size_t)s * 128 + lane], o0);
        o1 = fmaf(a, xl[(size_t)s * 128 + 64 + lane], o1);
    }
    ch2[(size_t)dst * 256 + lane] = o0 + bias[lane];
    ch2[(size_t)dst * 256 + 64 + lane] = o1 + bias[64 + lane];
}

// ---------------------------------------------------------------- latent GATv2 (wave per dst; 6 knn + self)
__global__ __launch_bounds__(256) void latent_gat_k(
    const float* __restrict__ xl, const float* __restrict__ xr,
    const int* __restrict__ knn, const float* __restrict__ att,
    const float* __restrict__ bias, float* __restrict__ ch2)
{
    int w = threadIdx.x >> 6, lane = threadIdx.x & 63;
    int dst = blockIdx.x * 4 + w;
    float xr0 = xr[(size_t)dst * 128 + lane], xr1 = xr[(size_t)dst * 128 + 64 + lane];
    float at0 = att[lane], at1 = att[64 + lane];
    int s[7];
#pragma unroll
    for (int j = 0; j < 6; ++j) s[j] = knn[(size_t)dst * 6 + j];
    s[6] = dst;
    float l[7];
#pragma unroll
    for (int j = 0; j < 7; ++j) {
        float h0 = xl[(size_t)s[j] * 128 + lane] + xr0;
        float h1 = xl[(size_t)s[j] * 128 + 64 + lane] + xr1;
        h0 = h0 > 0.f ? h0 : 0.2f * h0;
        h1 = h1 > 0.f ? h1 : 0.2f * h1;
        float p = h0 * at0 + h1 * at1;
#pragma unroll
        for (int off = 32; off; off >>= 1) p += __shfl_xor(p, off);
        l[j] = p;
    }
    float m = l[0];
#pragma unroll
    for (int j = 1; j < 7; ++j) m = fmaxf(m, l[j]);
    float sum = 0.f;
#pragma unroll
    for (int j = 0; j < 7; ++j) { l[j] = __expf(l[j] - m); sum += l[j]; }
    float inv = 1.f / sum;
    float o0 = 0.f, o1 = 0.f;
#pragma unroll
    for (int j = 0; j < 7; ++j) {
        float a = l[j] * inv;
        o0 = fmaf(a, xl[(size_t)s[j] * 128 + lane], o0);
        o1 = fmaf(a, xl[(size_t)s[j] * 128 + 64 + lane], o1);
    }
    ch2[(size_t)dst * 256 + 128 + lane] = o0 + bias[lane];
    ch2[(size_t)dst * 256 + 192 + lane] = o1 + bias[64 + lane];
}

// ---------------------------------------------------------------- launch
extern "C" void kernel_launch(void* const* d_in, const int* in_sizes, int n_in,
                              void* d_out, int out_size, void* d_ws, size_t ws_size,
                              hipStream_t stream)
{
    const float* x      = (const float*)d_in[0];
    const int*   ei     = (const int*)  d_in[1];   // [2][E]: src row then dst row
    const float* eattr  = (const float*)d_in[2];
    const float* W_sl   = (const float*)d_in[4];
    const float* b_sl   = (const float*)d_in[5];
    const float* W_sr   = (const float*)d_in[6];
    const float* b_sr   = (const float*)d_in[7];
    const float* att_s  = (const float*)d_in[8];
    const float* W_se   = (const float*)d_in[9];
    const float* bias_s = (const float*)d_in[10];
    const float* W_ll   = (const float*)d_in[11];
    const float* b_ll   = (const float*)d_in[12];
    const float* W_lr   = (const float*)d_in[13];
    const float* b_lr   = (const float*)d_in[14];
    const float* att_l  = (const float*)d_in[15];
    const float* bias_l = (const float*)d_in[16];
    const float* W_c    = (const float*)d_in[17];
    const float* b_c    = (const float*)d_in[18];
    const float* W_f1   = (const float*)d_in[19];
    const float* b_f1   = (const float*)d_in[20];
    const float* W_f2   = (const float*)d_in[21];
    const float* b_f2   = (const float*)d_in[22];
    float* out = (float*)d_out;

    char* wp = (char*)d_ws;
    auto take = [&](size_t bytes) { char* p = wp; wp += (bytes + 255) & ~(size_t)255; return p; };
    float* xl_s    = (float*)take((size_t)N * D * 4);
    float* xr_s    = (float*)take((size_t)N * D * 4);
    float* xl_l    = (float*)take((size_t)N * D * 4);
    float* xr_l    = (float*)take((size_t)N * D * 4);
    float* ch2     = (float*)take((size_t)N * 2 * D * 4);   // [N][256]; later reused as ffn hidden
    float* sqn     = (float*)take((size_t)N * 4);
    int*   knn_idx = (int*)  take((size_t)N * KN * 4);
    int*   deg     = (int*)  take((size_t)N * 4);           // also reused as cnt
    int*   rowptr  = (int*)  take((size_t)(N + 1) * 4);
    int*   csr_src = (int*)  take((size_t)E * 4);
    float* csr_ea  = (float*)take((size_t)E * 4);
    float* fused   = xl_s;   // alias: xl_s dead after spatial GAT
    float* hbuf    = ch2;    // alias: ch2 dead after fusion GEMM
    if ((size_t)(wp - (char*)d_ws) > ws_size) return;  // tripwire: insufficient workspace

    dim3 blk(256);

    // node transforms: xl_s/xr_s/xl_l/xr_l = x@W + b
    gemm_k<<<dim3(N / 64, 1), blk, 0, stream>>>(x, D, W_sl, D, b_sl, nullptr, xl_s, D, D, 0);
    gemm_k<<<dim3(N / 64, 1), blk, 0, stream>>>(x, D, W_sr, D, b_sr, nullptr, xr_s, D, D, 0);
    gemm_k<<<dim3(N / 64, 1), blk, 0, stream>>>(x, D, W_ll, D, b_ll, nullptr, xl_l, D, D, 0);
    gemm_k<<<dim3(N / 64, 1), blk, 0, stream>>>(x, D, W_lr, D, b_lr, nullptr, xr_l, D, D, 0);

    // kNN graph
    sqnorm_k<<<dim3(N / 4), blk, 0, stream>>>(x, sqn);
    knn_k<<<dim3(Bg * QT), blk, 0, stream>>>(x, sqn, knn_idx);

    // CSR of spatial edges by dst
    hipMemsetAsync(deg, 0, (size_t)N * 4, stream);
    hist_k<<<dim3(E / 256), blk, 0, stream>>>(ei + E, deg);
    scan_k<<<dim3(1), dim3(1024), 0, stream>>>(deg, rowptr);
    hipMemsetAsync(deg, 0, (size_t)N * 4, stream);  // reuse as scatter cursor
    scatter_k<<<dim3(E / 256), blk, 0, stream>>>(ei, ei + E, eattr, rowptr, deg, csr_src, csr_ea);

    // two GAT channels -> ch2 = [ch_sp | ch_lat]
    spatial_gat_k<<<dim3(N / 4), blk, 0, stream>>>(xl_s, xr_s, rowptr, csr_src, csr_ea,
                                                   att_s, W_se, bias_s, ch2);
    latent_gat_k<<<dim3(N / 4), blk, 0, stream>>>(xl_l, xr_l, knn_idx, att_l, bias_l, ch2);

    // fusion + FFN
    gemm_k<<<dim3(N / 64, 1), blk, 0, stream>>>(ch2, 2 * D, W_c, D, b_c, x, fused, D, 2 * D, 0);
    gemm_k<<<dim3(N / 64, 2), blk, 0, stream>>>(fused, D, W_f1, FF, b_f1, nullptr, hbuf, FF, D, 1);
    gemm_k<<<dim3(N / 64, 1), blk, 0, stream>>>(hbuf, FF, W_f2, D, b_f2, fused, out, D, FF, 1);
}

// Round 2
// 1145.287 us; speedup vs baseline: 1.7462x; 1.7462x over previous
//
#include <hip/hip_runtime.h>
#include <math.h>

// ---------------------------------------------------------------- constants
constexpr int N  = 40000;   // nodes
constexpr int D  = 128;     // latent dim
constexpr int E  = 640000;  // spatial edges
constexpr int Bg = 8;       // graphs
constexpr int Sg = 5000;    // nodes per graph
constexpr int KN = 6;       // knn
constexpr int FF = 256;     // ffn hidden
constexpr int LGCAP = 320;  // max in-degree supported in spatial GAT (actual ~45)
constexpr int HALF = 2500;  // candidate split per knn block
constexpr int TPH  = 40;    // ceil(HALF/64) candidate tiles per half

typedef short short8 __attribute__((ext_vector_type(8)));
typedef float f32x4  __attribute__((ext_vector_type(4)));

// ---------------------------------------------------------------- GEMM: out = A@W + bias (+res) (+relu6)
__global__ __launch_bounds__(256) void gemm_k(
    const float* __restrict__ A, int lda,
    const float* __restrict__ Wm, int ldw,
    const float* __restrict__ bias,
    const float* __restrict__ res,
    float* __restrict__ out, int ldo,
    int Kdim, int act)
{
    __shared__ float as[64][36];
    __shared__ float ws[32][128];
    int tid = threadIdx.x;
    int tr = tid >> 4, tc = tid & 15;
    int r0 = blockIdx.x * 64;
    int cb = blockIdx.y * 128;

    float acc[4][8];
#pragma unroll
    for (int j = 0; j < 4; ++j)
#pragma unroll
        for (int m = 0; m < 8; ++m) acc[j][m] = 0.f;

    for (int kt = 0; kt < Kdim; kt += 32) {
#pragma unroll
        for (int i = 0; i < 2; ++i) {
            int c2 = i * 256 + tid;
            int row = c2 >> 3, k4 = (c2 & 7) * 4;
            *(float4*)&as[row][k4] = *(const float4*)&A[(size_t)(r0 + row) * lda + kt + k4];
        }
#pragma unroll
        for (int i = 0; i < 4; ++i) {
            int c2 = i * 256 + tid;
            int row = c2 >> 5, c4 = (c2 & 31) * 4;
            *(float4*)&ws[row][c4] = *(const float4*)&Wm[(size_t)(kt + row) * ldw + cb + c4];
        }
        __syncthreads();
#pragma unroll 8
        for (int k = 0; k < 32; ++k) {
            float a[4], b[8];
#pragma unroll
            for (int j = 0; j < 4; ++j) a[j] = as[tr + 16 * j][k];
#pragma unroll
            for (int m = 0; m < 8; ++m) b[m] = ws[k][tc + 16 * m];
#pragma unroll
            for (int j = 0; j < 4; ++j)
#pragma unroll
                for (int m = 0; m < 8; ++m) acc[j][m] = fmaf(a[j], b[m], acc[j][m]);
        }
        __syncthreads();
    }
#pragma unroll
    for (int j = 0; j < 4; ++j) {
        int r = r0 + tr + 16 * j;
#pragma unroll
        for (int m = 0; m < 8; ++m) {
            int c = tc + 16 * m;
            float v = acc[j][m] + bias[cb + c];
            if (res) v += res[(size_t)r * 128 + c];
            if (act) v = fminf(fmaxf(v, 0.f), 6.f);
            out[(size_t)r * ldo + cb + c] = v;
        }
    }
}

// ---------------------------------------------------------------- per-row squared norm (wave per row)
__global__ __launch_bounds__(256) void sqnorm_k(const float* __restrict__ x, float* __restrict__ sqn)
{
    int w = threadIdx.x >> 6, lane = threadIdx.x & 63;
    int row = blockIdx.x * 4 + w;
    float v0 = x[(size_t)row * 128 + lane];
    float v1 = x[(size_t)row * 128 + 64 + lane];
    float s = v0 * v0 + v1 * v1;
#pragma unroll
    for (int off = 32; off; off >>= 1) s += __shfl_xor(s, off);
    if (lane == 0) sqn[row] = s;
}

// ---------------------------------------------------------------- x -> bf16 hi/lo split
__device__ __forceinline__ unsigned short f2bf(float f)
{
    unsigned int u = __float_as_uint(f);
    return (unsigned short)((u + 0x7fffu + ((u >> 16) & 1u)) >> 16);
}

__global__ __launch_bounds__(256) void cast_k(const float* __restrict__ x,
                                              unsigned short* __restrict__ xh,
                                              unsigned short* __restrict__ xl)
{
    size_t i = ((size_t)blockIdx.x * 256 + threadIdx.x) * 8;
    float4 v0 = *(const float4*)&x[i];
    float4 v1 = *(const float4*)&x[i + 4];
    float f[8] = {v0.x, v0.y, v0.z, v0.w, v1.x, v1.y, v1.z, v1.w};
    short8 hv, lv;
#pragma unroll
    for (int j = 0; j < 8; ++j) {
        unsigned short h = f2bf(f[j]);
        float hf = __uint_as_float(((unsigned int)h) << 16);
        hv[j] = (short)h;
        lv[j] = (short)f2bf(f[j] - hf);
    }
    *(short8*)&xh[i] = hv;
    *(short8*)&xl[i] = lv;
}

// ---------------------------------------------------------------- kNN prefilter via MFMA (bf16 hi/lo split)
// grid: 8 graphs x 40 query-blocks(128q) x 2 candidate-halves.
// block: 4 waves; wave w owns 32 queries (2 sets of 16 = mfma N dim).
// candidate tiles of 64 staged in LDS (hi+lo, XOR-swizzled rows).
// per-lane top-8 over its candidate quarter -> per-query top-12 (global ids).
__global__ __launch_bounds__(256) void knn_mfma_k(const unsigned short* __restrict__ xh,
                                                  const unsigned short* __restrict__ xl,
                                                  const float* __restrict__ sqn,
                                                  int* __restrict__ cand)
{
    __shared__ char lds[33024];               // 16KB hi + 16KB lo + 256B csq
    char* ldsH = lds;
    char* ldsL = lds + 16384;
    float* cs_s = (float*)(lds + 32768);

    int b = blockIdx.x;
    int g = b & 7, r = b >> 3;
    int csp = r & 1, qblk = r >> 1;
    int gbase = g * Sg;
    int cbase = csp * HALF;
    int tid = threadIdx.x;
    int w = tid >> 6, lane = tid & 63;
    int lg = lane >> 4, ln = lane & 15;
    int q0 = qblk * 128 + w * 32;

    // resident query B-frags: [qset][kstep], hi+lo
    short8 bh[2][4], bl[2][4];
#pragma unroll
    for (int s = 0; s < 2; ++s) {
        int q = q0 + s * 16 + ln;
        int qrow = gbase + (q < Sg ? q : Sg - 1);
#pragma unroll
        for (int ks = 0; ks < 4; ++ks) {
            bh[s][ks] = *(const short8*)&xh[(size_t)qrow * 128 + ks * 32 + lg * 8];
            bl[s][ks] = *(const short8*)&xl[(size_t)qrow * 128 + ks * 32 + lg * 8];
        }
    }

    float d8[2][8]; int i8[2][8]; float mx[2]; int sl[2];
#pragma unroll
    for (int s = 0; s < 2; ++s) {
        mx[s] = __builtin_inff(); sl[s] = 0;
#pragma unroll
        for (int t = 0; t < 8; ++t) { d8[s][t] = __builtin_inff(); i8[s][t] = -1; }
    }

    for (int t64 = 0; t64 < TPH; ++t64) {
        int c0 = cbase + t64 * 64;
        __syncthreads();
        // stage 64 cand rows hi+lo, swizzled: byte ^= (row&7)<<4
#pragma unroll
        for (int i = 0; i < 4; ++i) {
            int c = i * 256 + tid;            // 1024 chunks of 16B
            int row = c >> 4, slot = c & 15;
            int cr = c0 + row;
            int grow = gbase + (cr < Sg ? cr : Sg - 1);
            short8 vh = *(const short8*)&xh[(size_t)grow * 128 + slot * 8];
            short8 vl = *(const short8*)&xl[(size_t)grow * 128 + slot * 8];
            int db = row * 256 + ((slot * 16) ^ ((row & 7) << 4));
            *(short8*)(ldsH + db) = vh;
            *(short8*)(ldsL + db) = vl;
        }
        if (tid < 64) {
            int cl = c0 + tid;
            cs_s[tid] = (cl < cbase + HALF && cl < Sg) ? sqn[gbase + cl] : __builtin_inff();
        }
        __syncthreads();

#pragma unroll
        for (int g16 = 0; g16 < 4; ++g16) {
            f32x4 acc0 = {0.f, 0.f, 0.f, 0.f};
            f32x4 acc1 = {0.f, 0.f, 0.f, 0.f};
            int rr = g16 * 16 + ln;
            int rsw = (rr & 7) << 4;
#pragma unroll
            for (int ks = 0; ks < 4; ++ks) {
                int ba = rr * 256 + ((lg * 16 + ks * 64) ^ rsw);
                short8 ah = *(const short8*)(ldsH + ba);
                short8 al = *(const short8*)(ldsL + ba);
                acc0 = __builtin_amdgcn_mfma_f32_16x16x32_bf16(ah, bh[0][ks], acc0, 0, 0, 0);
                acc0 = __builtin_amdgcn_mfma_f32_16x16x32_bf16(ah, bl[0][ks], acc0, 0, 0, 0);
                acc0 = __builtin_amdgcn_mfma_f32_16x16x32_bf16(al, bh[0][ks], acc0, 0, 0, 0);
                acc1 = __builtin_amdgcn_mfma_f32_16x16x32_bf16(ah, bh[1][ks], acc1, 0, 0, 0);
                acc1 = __builtin_amdgcn_mfma_f32_16x16x32_bf16(ah, bl[1][ks], acc1, 0, 0, 0);
                acc1 = __builtin_amdgcn_mfma_f32_16x16x32_bf16(al, bh[1][ks], acc1, 0, 0, 0);
            }
            f32x4 cv = *(const f32x4*)&cs_s[g16 * 16 + lg * 4];
#pragma unroll
            for (int s = 0; s < 2; ++s) {
                int q = q0 + s * 16 + ln;
                const f32x4& ac = s ? acc1 : acc0;
#pragma unroll
                for (int rg = 0; rg < 4; ++rg) {
                    int c = c0 + g16 * 16 + lg * 4 + rg;
                    float dv = fmaf(-2.f, ac[rg], cv[rg]);
                    bool valid = (c < cbase + HALF) && (c < Sg) && (c != q);
                    if (valid && dv < mx[s]) {
#pragma unroll
                        for (int t = 0; t < 8; ++t)
                            if (t == sl[s]) { d8[s][t] = dv; i8[s][t] = gbase + c; }
                        float m2 = d8[s][0]; int s2 = 0;
#pragma unroll
                        for (int t = 1; t < 8; ++t)
                            if (d8[s][t] > m2) { m2 = d8[s][t]; s2 = t; }
                        mx[s] = m2; sl[s] = s2;
                    }
                }
            }
        }
    }

    // merge 4 lane-group partials -> per-query top-12 (reuse LDS)
    __syncthreads();
    float* mb = (float*)lds;
#pragma unroll
    for (int s = 0; s < 2; ++s) {
        int qloc = w * 32 + s * 16 + ln;
        int off = (qloc * 4 + lg) * 16;
#pragma unroll
        for (int t = 0; t < 8; ++t) {
            mb[off + 2 * t]     = d8[s][t];
            mb[off + 2 * t + 1] = __int_as_float(i8[s][t]);
        }
    }
    __syncthreads();
    if (tid < 128) {
        int q = qblk * 128 + tid;
        if (q < Sg) {
            float d12[12]; int i12[12]; float m12 = __builtin_inff(); int s12 = 0;
#pragma unroll
            for (int t = 0; t < 12; ++t) { d12[t] = __builtin_inff(); i12[t] = -1; }
            for (int gg = 0; gg < 4; ++gg) {
                int off = (tid * 4 + gg) * 16;
#pragma unroll
                for (int t = 0; t < 8; ++t) {
                    float dv = mb[off + 2 * t];
                    int ci = __float_as_int(mb[off + 2 * t + 1]);
                    if (dv < m12) {
#pragma unroll
                        for (int u = 0; u < 12; ++u)
                            if (u == s12) { d12[u] = dv; i12[u] = ci; }
                        float m2 = d12[0]; int s2 = 0;
#pragma unroll
                        for (int u = 1; u < 12; ++u)
                            if (d12[u] > m2) { m2 = d12[u]; s2 = u; }
                        m12 = m2; s12 = s2;
                    }
                }
            }
            int* cp = &cand[(size_t)(gbase + q) * 24 + csp * 12];
#pragma unroll
            for (int j = 0; j < 12; ++j) cp[j] = i12[j];
        }
    }
}

// ---------------------------------------------------------------- exact fp32 re-rank of <=24 candidates
// serial ascending-k fmaf chain == round-1 knn_k accumulation order (bitwise).
__global__ __launch_bounds__(256) void knn_rerank_k(const float* __restrict__ x,
                                                    const float* __restrict__ sqn,
                                                    const int* __restrict__ cand,
                                                    int* __restrict__ knn_idx)
{
    int q = blockIdx.x * 256 + threadIdx.x;
    if (q >= N) return;
    const float* xq = x + (size_t)q * 128;
    float d6[6]; int i6[6]; float mx = __builtin_inff(); int sl = 0;
#pragma unroll
    for (int t = 0; t < 6; ++t) { d6[t] = __builtin_inff(); i6[t] = -1; }
    for (int j = 0; j < 24; ++j) {
        int c = cand[(size_t)q * 24 + j];
        if (c < 0) continue;
        const float* xc = x + (size_t)c * 128;
        float acc = 0.f;
        for (int k = 0; k < 128; ++k) acc = fmaf(xq[k], xc[k], acc);
        float dv = fmaf(-2.f, acc, sqn[c]);
        if (dv < mx) {
#pragma unroll
            for (int t = 0; t < 6; ++t)
                if (t == sl) { d6[t] = dv; i6[t] = c; }
            float m2 = d6[0]; int s2 = 0;
#pragma unroll
            for (int t = 1; t < 6; ++t)
                if (d6[t] > m2) { m2 = d6[t]; s2 = t; }
            mx = m2; sl = s2;
        }
    }
#pragma unroll
    for (int t = 0; t < 6; ++t) knn_idx[(size_t)q * 6 + t] = i6[t];
}

// ---------------------------------------------------------------- CSR build
__global__ __launch_bounds__(256) void hist_k(const int* __restrict__ dstA, int* __restrict__ deg)
{
    int e = blockIdx.x * 256 + threadIdx.x;
    atomicAdd(&deg[dstA[e]], 1);
}

__global__ __launch_bounds__(1024) void scan_k(const int* __restrict__ deg, int* __restrict__ rowptr)
{
    __shared__ int ps[1024];
    int t = threadIdx.x;
    const int chunk = 40;
    int base = t * chunk;
    int s = 0;
    for (int k = 0; k < chunk; ++k) { int i = base + k; if (i < N) s += deg[i]; }
    ps[t] = s;
    __syncthreads();
    for (int off = 1; off < 1024; off <<= 1) {
        int v = (t >= off) ? ps[t - off] : 0;
        __syncthreads();
        ps[t] += v;
        __syncthreads();
    }
    int run = ps[t] - s;
    for (int k = 0; k < chunk; ++k) {
        int i = base + k;
        if (i < N) { rowptr[i] = run; run += deg[i]; }
    }
    if (t == 0) rowptr[N] = E;
}

__global__ __launch_bounds__(256) void scatter_k(const int* __restrict__ srcA, const int* __restrict__ dstA,
                                                 const float* __restrict__ ea,
                                                 const int* __restrict__ rowptr, int* __restrict__ cnt,
                                                 int* __restrict__ csr_src, float* __restrict__ csr_ea)
{
    int e = blockIdx.x * 256 + threadIdx.x;
    int d = dstA[e];
    int pos = rowptr[d] + atomicAdd(&cnt[d], 1);
    csr_src[pos] = srcA[e];
    csr_ea[pos] = ea[e];
}

// ---------------------------------------------------------------- spatial GATv2 (wave per dst node)
__global__ __launch_bounds__(256) void spatial_gat_k(
    const float* __restrict__ xl, const float* __restrict__ xr,
    const int* __restrict__ rowptr, const int* __restrict__ csr_src, const float* __restrict__ csr_ea,
    const float* __restrict__ att, const float* __restrict__ wse, const float* __restrict__ bias,
    float* __restrict__ ch2)
{
    __shared__ float lg[4][LGCAP];
    int w = threadIdx.x >> 6, lane = threadIdx.x & 63;
    int dst = blockIdx.x * 4 + w;
    int base = rowptr[dst];
    int deg = rowptr[dst + 1] - base;
    if (deg > LGCAP) deg = LGCAP;
    float xr0 = xr[(size_t)dst * 128 + lane], xr1 = xr[(size_t)dst * 128 + 64 + lane];
    float at0 = att[lane], at1 = att[64 + lane];
    float we0 = wse[lane], we1 = wse[64 + lane];
    float m = -1e30f;
    for (int i = 0; i < deg; ++i) {
        int s = csr_src[base + i];
        float ea = csr_ea[base + i];
        float h0 = xl[(size_t)s * 128 + lane] + xr0 + ea * we0;
        float h1 = xl[(size_t)s * 128 + 64 + lane] + xr1 + ea * we1;
        h0 = h0 > 0.f ? h0 : 0.2f * h0;
        h1 = h1 > 0.f ? h1 : 0.2f * h1;
        float p = h0 * at0 + h1 * at1;
#pragma unroll
        for (int off = 32; off; off >>= 1) p += __shfl_xor(p, off);
        if (lane == 0) lg[w][i] = p;
        m = fmaxf(m, p);
    }
    __syncthreads();
    float sum = 0.f;
    for (int i = lane; i < deg; i += 64) {
        float ev = __expf(lg[w][i] - m);
        lg[w][i] = ev;
        sum += ev;
    }
#pragma unroll
    for (int off = 32; off; off >>= 1) sum += __shfl_xor(sum, off);
    float inv = 1.f / sum;
    __syncthreads();
    float o0 = 0.f, o1 = 0.f;
    for (int i = 0; i < deg; ++i) {
        float a = lg[w][i] * inv;
        int s = csr_src[base + i];
        o0 = fmaf(a, xl[(size_t)s * 128 + lane], o0);
        o1 = fmaf(a, xl[(size_t)s * 128 + 64 + lane], o1);
    }
    ch2[(size_t)dst * 256 + lane] = o0 + bias[lane];
    ch2[(size_t)dst * 256 + 64 + lane] = o1 + bias[64 + lane];
}

// ---------------------------------------------------------------- latent GATv2 (wave per dst; 6 knn + self)
__global__ __launch_bounds__(256) void latent_gat_k(
    const float* __restrict__ xl, const float* __restrict__ xr,
    const int* __restrict__ knn, const float* __restrict__ att,
    const float* __restrict__ bias, float* __restrict__ ch2)
{
    int w = threadIdx.x >> 6, lane = threadIdx.x & 63;
    int dst = blockIdx.x * 4 + w;
    float xr0 = xr[(size_t)dst * 128 + lane], xr1 = xr[(size_t)dst * 128 + 64 + lane];
    float at0 = att[lane], at1 = att[64 + lane];
    int s[7];
#pragma unroll
    for (int j = 0; j < 6; ++j) s[j] = knn[(size_t)dst * 6 + j];
    s[6] = dst;
    float l[7];
#pragma unroll
    for (int j = 0; j < 7; ++j) {
        float h0 = xl[(size_t)s[j] * 128 + lane] + xr0;
        float h1 = xl[(size_t)s[j] * 128 + 64 + lane] + xr1;
        h0 = h0 > 0.f ? h0 : 0.2f * h0;
        h1 = h1 > 0.f ? h1 : 0.2f * h1;
        float p = h0 * at0 + h1 * at1;
#pragma unroll
        for (int off = 32; off; off >>= 1) p += __shfl_xor(p, off);
        l[j] = p;
    }
    float m = l[0];
#pragma unroll
    for (int j = 1; j < 7; ++j) m = fmaxf(m, l[j]);
    float sum = 0.f;
#pragma unroll
    for (int j = 0; j < 7; ++j) { l[j] = __expf(l[j] - m); sum += l[j]; }
    float inv = 1.f / sum;
    float o0 = 0.f, o1 = 0.f;
#pragma unroll
    for (int j = 0; j < 7; ++j) {
        float a = l[j] * inv;
        o0 = fmaf(a, xl[(size_t)s[j] * 128 + lane], o0);
        o1 = fmaf(a, xl[(size_t)s[j] * 128 + 64 + lane], o1);
    }
    ch2[(size_t)dst * 256 + 128 + lane] = o0 + bias[lane];
    ch2[(size_t)dst * 256 + 192 + lane] = o1 + bias[64 + lane];
}

// ---------------------------------------------------------------- launch
extern "C" void kernel_launch(void* const* d_in, const int* in_sizes, int n_in,
                              void* d_out, int out_size, void* d_ws, size_t ws_size,
                              hipStream_t stream)
{
    const float* x      = (const float*)d_in[0];
    const int*   ei     = (const int*)  d_in[1];
    const float* eattr  = (const float*)d_in[2];
    const float* W_sl   = (const float*)d_in[4];
    const float* b_sl   = (const float*)d_in[5];
    const float* W_sr   = (const float*)d_in[6];
    const float* b_sr   = (const float*)d_in[7];
    const float* att_s  = (const float*)d_in[8];
    const float* W_se   = (const float*)d_in[9];
    const float* bias_s = (const float*)d_in[10];
    const float* W_ll   = (const float*)d_in[11];
    const float* b_ll   = (const float*)d_in[12];
    const float* W_lr   = (const float*)d_in[13];
    const float* b_lr   = (const float*)d_in[14];
    const float* att_l  = (const float*)d_in[15];
    const float* bias_l = (const float*)d_in[16];
    const float* W_c    = (const float*)d_in[17];
    const float* b_c    = (const float*)d_in[18];
    const float* W_f1   = (const float*)d_in[19];
    const float* b_f1   = (const float*)d_in[20];
    const float* W_f2   = (const float*)d_in[21];
    const float* b_f2   = (const float*)d_in[22];
    float* out = (float*)d_out;

    char* wp = (char*)d_ws;
    auto take = [&](size_t bytes) { char* p = wp; wp += (bytes + 255) & ~(size_t)255; return p; };
    float* xl_s    = (float*)take((size_t)N * D * 4);
    float* xr_s    = (float*)take((size_t)N * D * 4);
    float* xl_l    = (float*)take((size_t)N * D * 4);
    float* xr_l    = (float*)take((size_t)N * D * 4);
    float* ch2     = (float*)take((size_t)N * 2 * D * 4);
    float* sqn     = (float*)take((size_t)N * 4);
    int*   knn_idx = (int*)  take((size_t)N * KN * 4);
    int*   deg     = (int*)  take((size_t)N * 4);
    int*   rowptr  = (int*)  take((size_t)(N + 1) * 4);
    int*   csr_src = (int*)  take((size_t)E * 4);
    float* csr_ea  = (float*)take((size_t)E * 4);
    unsigned short* x_hi = (unsigned short*)take((size_t)N * D * 2);
    unsigned short* x_lo = (unsigned short*)take((size_t)N * D * 2);
    int*   knn_cand = (int*)take((size_t)N * 24 * 4);
    float* fused   = xl_s;
    float* hbuf    = ch2;
    if ((size_t)(wp - (char*)d_ws) > ws_size) return;

    dim3 blk(256);

    // node transforms
    gemm_k<<<dim3(N / 64, 1), blk, 0, stream>>>(x, D, W_sl, D, b_sl, nullptr, xl_s, D, D, 0);
    gemm_k<<<dim3(N / 64, 1), blk, 0, stream>>>(x, D, W_sr, D, b_sr, nullptr, xr_s, D, D, 0);
    gemm_k<<<dim3(N / 64, 1), blk, 0, stream>>>(x, D, W_ll, D, b_ll, nullptr, xl_l, D, D, 0);
    gemm_k<<<dim3(N / 64, 1), blk, 0, stream>>>(x, D, W_lr, D, b_lr, nullptr, xr_l, D, D, 0);

    // kNN graph: bf16 hi/lo MFMA prefilter -> exact fp32 re-rank
    sqnorm_k<<<dim3(N / 4), blk, 0, stream>>>(x, sqn);
    cast_k<<<dim3((N * D) / (256 * 8)), blk, 0, stream>>>(x, x_hi, x_lo);
    knn_mfma_k<<<dim3(Bg * TPH * 2 * 1), blk, 0, stream>>>(x_hi, x_lo, sqn, knn_cand);
    knn_rerank_k<<<dim3((N + 255) / 256), blk, 0, stream>>>(x, sqn, knn_cand, knn_idx);

    // CSR of spatial edges by dst
    hipMemsetAsync(deg, 0, (size_t)N * 4, stream);
    hist_k<<<dim3(E / 256), blk, 0, stream>>>(ei + E, deg);
    scan_k<<<dim3(1), dim3(1024), 0, stream>>>(deg, rowptr);
    hipMemsetAsync(deg, 0, (size_t)N * 4, stream);
    scatter_k<<<dim3(E / 256), blk, 0, stream>>>(ei, ei + E, eattr, rowptr, deg, csr_src, csr_ea);

    // two GAT channels -> ch2 = [ch_sp | ch_lat]
    spatial_gat_k<<<dim3(N / 4), blk, 0, stream>>>(xl_s, xr_s, rowptr, csr_src, csr_ea,
                                                   att_s, W_se, bias_s, ch2);
    latent_gat_k<<<dim3(N / 4), blk, 0, stream>>>(xl_l, xr_l, knn_idx, att_l, bias_l, ch2);

    // fusion + FFN
    gemm_k<<<dim3(N / 64, 1), blk, 0, stream>>>(ch2, 2 * D, W_c, D, b_c, x, fused, D, 2 * D, 0);
    gemm_k<<<dim3(N / 64, 2), blk, 0, stream>>>(fused, D, W_f1, FF, b_f1, nullptr, hbuf, FF, D, 1);
    gemm_k<<<dim3(N / 64, 1), blk, 0, stream>>>(hbuf, FF, W_f2, D, b_f2, fused, out, D, FF, 1);
}